// Round 1
// baseline (68.131 us; speedup 1.0000x reference)
//
#include <hip/hip_runtime.h>
#include <hip/hip_fp16.h>
#include <math.h>

#define NV 10475
#define NDS 2048
#define NHAND 1554
#define NHA 777
#define NCONTACT 300

#define GEO_THRESH 0.3f
#define EXT_THRESH 0.02f
#define A1c 0.04f
#define A2c 0.04f
#define B1c 0.07f
#define B2c 0.06f
#define C1c 0.01f
#define C2c 0.01f
#define D1c 0.023f
#define D2c 0.02f
#define CONTACT_W 0.5f
#define INSIDE_W 0.5f
#define HAND_W 1.0f

// Kernel 1: fp16-round vertices -> float4 (aligned), zero inside[] flags.
__global__ void prep_kernel(const float* __restrict__ verts,
                            float4* __restrict__ vq,
                            int* __restrict__ inside) {
    int i = blockIdx.x * blockDim.x + threadIdx.x;
    if (i < NV) {
        float x = __half2float(__float2half(verts[3 * i + 0]));
        float y = __half2float(__float2half(verts[3 * i + 1]));
        float z = __half2float(__float2half(verts[3 * i + 2]));
        vq[i] = make_float4(x, y, z, 0.0f);
        inside[i] = 0;
    }
}

// Kernel 2: one block per query row. Masked min squared distance over all NV
// candidates; optional fused gdi (min of geodist[row, cidx[j]] over 300 cols).
__global__ void minrow_kernel(const float* __restrict__ geodist,
                              const float4* __restrict__ vq,
                              const int* __restrict__ qidx,
                              const int* __restrict__ cidx,
                              float* __restrict__ out_min,
                              float* __restrict__ out_gdi) {
    const int q = qidx[blockIdx.x];
    const float* __restrict__ grow = geodist + (size_t)q * NV;
    const float4 p = vq[q];

    float best = INFINITY;
    for (int n = threadIdx.x; n < NV; n += blockDim.x) {
        float g = grow[n];
        float4 w = vq[n];
        float dx = p.x - w.x;
        float dy = p.y - w.y;
        float dz = p.z - w.z;
        float d2 = dx * dx + dy * dy + dz * dz;
        if (g < GEO_THRESH) d2 = INFINITY;   // geodesically-near -> excluded
        best = fminf(best, d2);
    }

    __shared__ float sred[8];
    int lane = threadIdx.x & 63;
    int wave = threadIdx.x >> 6;
    #pragma unroll
    for (int off = 32; off > 0; off >>= 1)
        best = fminf(best, __shfl_down(best, off));
    if (lane == 0) sred[wave] = best;
    __syncthreads();
    if (threadIdx.x == 0) {
        float b = sred[0];
        for (int w = 1; w < (int)(blockDim.x >> 6); ++w) b = fminf(b, sred[w]);
        out_min[blockIdx.x] = sqrtf(b + 1e-12f);
    }

    if (out_gdi != nullptr) {
        __syncthreads();
        float gb = INFINITY;
        for (int j = threadIdx.x; j < NCONTACT; j += blockDim.x)
            gb = fminf(gb, grow[cidx[j]]);
        #pragma unroll
        for (int off = 32; off > 0; off >>= 1)
            gb = fminf(gb, __shfl_down(gb, off));
        if (lane == 0) sred[wave] = gb;
        __syncthreads();
        if (threadIdx.x == 0) {
            float b = sred[0];
            for (int w = 1; w < (int)(blockDim.x >> 6); ++w) b = fminf(b, sred[w]);
            out_gdi[blockIdx.x] = b;
        }
    }
}

// Kernel 3: scatter inside flags: inside[ds[i]] |= (min <= EXT_THRESH)
__global__ void scatter_inside_kernel(const float* __restrict__ ds_min,
                                      const int* __restrict__ ds,
                                      int* __restrict__ inside) {
    int i = blockIdx.x * blockDim.x + threadIdx.x;
    if (i < NDS) {
        if (!(ds_min[i] > EXT_THRESH)) {
            atomicOr(&inside[ds[i]], 1);
        }
    }
}

// Kernel 4: single-block final reduction to the scalar loss.
__global__ void finalize_kernel(const float* __restrict__ ds_min,
                                const float* __restrict__ gdi,
                                const int* __restrict__ ds,
                                const float* __restrict__ hand_min,
                                const float* __restrict__ hw,
                                const int* __restrict__ hand_idx,
                                const int* __restrict__ inside,
                                float* __restrict__ out) {
    // acc: 0 contact_sum, 1 contact_cnt, 2 inside_sum, 3 inside_cnt,
    //      4 l_out_sum, 5 l_out_cnt, 6 r_out_sum, 7 r_out_cnt,
    //      8 l_in_sum, 9 l_in_cnt, 10 r_in_sum, 11 r_in_cnt
    float acc[12];
    #pragma unroll
    for (int k = 0; k < 12; ++k) acc[k] = 0.0f;

    const int tid = threadIdx.x;

    for (int i = tid; i < NDS; i += blockDim.x) {
        float m = ds_min[i];
        bool ins = inside[ds[i]] != 0;
        if (!ins) {
            float w = 1.0f / (5.0f * gdi[i] + 1.0f);
            acc[0] += A1c * w * tanhf(m / A2c);
            acc[1] += 1.0f;
        } else {
            acc[2] += B1c * tanhf(m / B2c);
            acc[3] += 1.0f;
        }
    }

    for (int h = tid; h < NHAND; h += blockDim.x) {
        float m = hand_min[h];
        bool ins = inside[hand_idx[h]] != 0;
        float w = -0.1f * hw[h] + 1.0f;
        float o = w * C1c * tanhf(m / C2c);
        float ii = D1c * tanhf(m / D2c);
        if (h < NHA) {
            if (!ins) { acc[4] += o;  acc[5] += 1.0f; }
            else      { acc[8] += ii; acc[9] += 1.0f; }
        } else {
            if (!ins) { acc[6]  += o;  acc[7]  += 1.0f; }
            else      { acc[10] += ii; acc[11] += 1.0f; }
        }
    }

    __shared__ float red[4][12];
    int lane = tid & 63;
    int wave = tid >> 6;
    #pragma unroll
    for (int k = 0; k < 12; ++k) {
        float v = acc[k];
        #pragma unroll
        for (int off = 32; off > 0; off >>= 1)
            v += __shfl_down(v, off);
        acc[k] = v;
    }
    if (lane == 0) {
        #pragma unroll
        for (int k = 0; k < 12; ++k) red[wave][k] = acc[k];
    }
    __syncthreads();
    if (tid == 0) {
        float t[12];
        #pragma unroll
        for (int k = 0; k < 12; ++k)
            t[k] = red[0][k] + red[1][k] + red[2][k] + red[3][k];
        float contactloss = CONTACT_W * (t[0] / fmaxf(t[1], 1.0f));
        float insideloss  = INSIDE_W  * (t[2] / fmaxf(t[3], 1.0f));
        float hand_out = t[4] / fmaxf(t[5], 1.0f) + t[6]  / fmaxf(t[7], 1.0f);
        float hand_in  = t[8] / fmaxf(t[9], 1.0f) + t[10] / fmaxf(t[11], 1.0f);
        out[0] = contactloss + insideloss + HAND_W * (hand_out + hand_in);
    }
}

extern "C" void kernel_launch(void* const* d_in, const int* in_sizes, int n_in,
                              void* d_out, int out_size, void* d_ws, size_t ws_size,
                              hipStream_t stream) {
    const float* vertices   = (const float*)d_in[0];   // [1,NV,3]
    const float* geodist    = (const float*)d_in[1];   // [NV,NV]
    const float* hand_w     = (const float*)d_in[2];   // [NHAND]
    const int*   ds         = (const int*)d_in[3];     // [NDS]
    const int*   hand_idx   = (const int*)d_in[4];     // [NHAND]
    const int*   cidx       = (const int*)d_in[5];     // [NCONTACT]
    float* out = (float*)d_out;

    // workspace layout
    float4* vq      = (float4*)d_ws;                   // NV float4
    float* hand_min = (float*)(vq + NV);               // NHAND
    float* ds_min   = hand_min + NHAND;                // NDS
    float* gdi      = ds_min + NDS;                    // NDS
    int*   inside   = (int*)(gdi + NDS);               // NV

    prep_kernel<<<(NV + 255) / 256, 256, 0, stream>>>(vertices, vq, inside);

    minrow_kernel<<<NHAND, 256, 0, stream>>>(geodist, vq, hand_idx, cidx,
                                             hand_min, nullptr);
    minrow_kernel<<<NDS, 256, 0, stream>>>(geodist, vq, ds, cidx,
                                           ds_min, gdi);

    scatter_inside_kernel<<<(NDS + 255) / 256, 256, 0, stream>>>(ds_min, ds, inside);

    finalize_kernel<<<1, 256, 0, stream>>>(ds_min, gdi, ds, hand_min, hand_w,
                                           hand_idx, inside, out);
}

// Round 2
// 61.002 us; speedup vs baseline: 1.1169x; 1.1169x over previous
//
#include <hip/hip_runtime.h>
#include <hip/hip_fp16.h>
#include <math.h>

#define NV 10475
#define NDS 2048
#define NHAND 1554
#define NHA 777
#define NCONTACT 300
#define NQ (NHAND + NDS)            // 3602 query rows total

#define GDI_CHUNKS 8
#define GDI_ROWS ((NCONTACT + GDI_CHUNKS - 1) / GDI_CHUNKS)  // 38

#define GEO_THRESH 0.3f
#define EXT_THRESH 0.02f
#define A1c 0.04f
#define A2c 0.04f
#define B1c 0.07f
#define B2c 0.06f
#define C1c 0.01f
#define C2c 0.01f
#define D1c 0.023f
#define D2c 0.02f
#define CONTACT_W 0.5f
#define INSIDE_W 0.5f
#define HAND_W 1.0f

#define SCAN_BLOCKS 512
#define SCAN_THREADS 512

// ---------------------------------------------------------------------------
// Kernel 1 (grid 41 x (1+GDI_CHUNKS)):
//   y==0 : fp16-round vertices -> packed half arrays; zero inside[]
//   y>0  : gdi partials: stream GDI_ROWS contact rows, column-wise min
//          (uses geodist symmetry: geodist[r, c] == geodist[c, r])
// ---------------------------------------------------------------------------
__global__ void prep_gdi_kernel(const float* __restrict__ verts,
                                const float* __restrict__ geodist,
                                const int* __restrict__ cidx,
                                __half2* __restrict__ gxy,
                                __half* __restrict__ gz,
                                int* __restrict__ inside,
                                float* __restrict__ pgdi) {
    const int n = blockIdx.x * 256 + threadIdx.x;
    if (blockIdx.y == 0) {
        if (n < NV) {
            __half hx = __float2half(verts[3 * n + 0]);
            __half hy = __float2half(verts[3 * n + 1]);
            __half hz = __float2half(verts[3 * n + 2]);
            gxy[n] = __halves2half2(hx, hy);
            gz[n] = hz;
            inside[n] = 0;
        }
    } else {
        const int c = blockIdx.y - 1;
        const int j0 = c * GDI_ROWS;
        const int j1 = (j0 + GDI_ROWS < NCONTACT) ? (j0 + GDI_ROWS) : NCONTACT;
        if (n < NV) {
            float m = INFINITY;
            for (int j = j0; j < j1; ++j) {
                m = fminf(m, geodist[(size_t)cidx[j] * NV + n]);
            }
            pgdi[(size_t)c * NV + n] = m;
        }
    }
}

// ---------------------------------------------------------------------------
// Kernel 2: persistent masked-min scan. Each block stages all NV candidate
// points (fp16-packed, 62.9 KB LDS) once, then loops over query rows.
// ---------------------------------------------------------------------------
__device__ __forceinline__ float cand_min(float best, float g, __half2 cxy,
                                          __half cz, float px, float py, float pz) {
    float2 c = __half22float2(cxy);
    float dx = px - c.x;
    float dy = py - c.y;
    float dz = pz - __half2float(cz);
    float d2 = fmaf(dx, dx, fmaf(dy, dy, dz * dz));
    d2 = (g < GEO_THRESH) ? INFINITY : d2;
    return fminf(best, d2);
}

__global__ __launch_bounds__(SCAN_THREADS, 2)
void scan_kernel(const float* __restrict__ geodist,
                 const __half2* __restrict__ gxy,
                 const __half* __restrict__ gz,
                 const int* __restrict__ hand_idx,
                 const int* __restrict__ ds,
                 float* __restrict__ hand_min,
                 float* __restrict__ ds_min,
                 int* __restrict__ inside) {
    __shared__ __half2 sxy[NV];
    __shared__ __half sz[NV + 1];
    __shared__ float sred[SCAN_THREADS / 64];

    const int tid = threadIdx.x;

    for (int n = tid; n < NV; n += SCAN_THREADS) {
        sxy[n] = gxy[n];
        sz[n] = gz[n];
    }
    __syncthreads();

    const int lane = tid & 63;
    const int wave = tid >> 6;

    for (int qi = blockIdx.x; qi < NQ; qi += gridDim.x) {
        const bool is_ds = (qi >= NHAND);
        const int q = is_ds ? ds[qi - NHAND] : hand_idx[qi];
        const float* __restrict__ grow = geodist + (size_t)q * NV;

        const float2 pxy = __half22float2(sxy[q]);
        const float px = pxy.x, py = pxy.y;
        const float pz = __half2float(sz[q]);

        const int pre = (4 - ((int)((size_t)q * NV) & 3)) & 3;  // elems to 16B align
        const int nvec = (NV - pre) >> 2;
        const int rem = (NV - pre) & 3;
        const int tail0 = pre + (nvec << 2);

        float best = INFINITY;

        if (tid < pre) {
            best = cand_min(best, grow[tid], sxy[tid], sz[tid], px, py, pz);
        }
        if (tid < rem) {
            const int n = tail0 + tid;
            best = cand_min(best, grow[n], sxy[n], sz[n], px, py, pz);
        }

        const float4* __restrict__ grow4 = (const float4*)(grow + pre);
        for (int j = tid; j < nvec; j += SCAN_THREADS) {
            const float4 g4 = grow4[j];
            const int n = pre + (j << 2);
            best = cand_min(best, g4.x, sxy[n + 0], sz[n + 0], px, py, pz);
            best = cand_min(best, g4.y, sxy[n + 1], sz[n + 1], px, py, pz);
            best = cand_min(best, g4.z, sxy[n + 2], sz[n + 2], px, py, pz);
            best = cand_min(best, g4.w, sxy[n + 3], sz[n + 3], px, py, pz);
        }

        #pragma unroll
        for (int off = 32; off > 0; off >>= 1)
            best = fminf(best, __shfl_down(best, off));
        if (lane == 0) sred[wave] = best;
        __syncthreads();
        if (tid == 0) {
            float b = sred[0];
            #pragma unroll
            for (int w = 1; w < SCAN_THREADS / 64; ++w) b = fminf(b, sred[w]);
            const float d = sqrtf(b + 1e-12f);
            if (is_ds) {
                ds_min[qi - NHAND] = d;
                if (!(d > EXT_THRESH)) atomicOr(&inside[q], 1);
            } else {
                hand_min[qi] = d;
            }
        }
        __syncthreads();  // sred reused next query
    }
}

// ---------------------------------------------------------------------------
// Kernel 3: single-block finalize. Combines gdi partials, computes all masked
// means, writes the scalar loss.
// ---------------------------------------------------------------------------
__global__ void finalize_kernel(const float* __restrict__ ds_min,
                                const float* __restrict__ pgdi,
                                const int* __restrict__ ds,
                                const float* __restrict__ hand_min,
                                const float* __restrict__ hw,
                                const int* __restrict__ hand_idx,
                                const int* __restrict__ inside,
                                float* __restrict__ out) {
    // acc: 0 contact_sum, 1 contact_cnt, 2 inside_sum, 3 inside_cnt,
    //      4 l_out_sum, 5 l_out_cnt, 6 r_out_sum, 7 r_out_cnt,
    //      8 l_in_sum, 9 l_in_cnt, 10 r_in_sum, 11 r_in_cnt
    float acc[12];
    #pragma unroll
    for (int k = 0; k < 12; ++k) acc[k] = 0.0f;

    const int tid = threadIdx.x;
    const int nthr = blockDim.x;

    for (int i = tid; i < NDS; i += nthr) {
        const float m = ds_min[i];
        const int v = ds[i];
        const bool ins = inside[v] != 0;
        if (!ins) {
            float gdi = pgdi[v];
            #pragma unroll
            for (int c = 1; c < GDI_CHUNKS; ++c)
                gdi = fminf(gdi, pgdi[(size_t)c * NV + v]);
            const float w = 1.0f / (5.0f * gdi + 1.0f);
            acc[0] += A1c * w * tanhf(m / A2c);
            acc[1] += 1.0f;
        } else {
            acc[2] += B1c * tanhf(m / B2c);
            acc[3] += 1.0f;
        }
    }

    for (int h = tid; h < NHAND; h += nthr) {
        const float m = hand_min[h];
        const bool ins = inside[hand_idx[h]] != 0;
        const float w = -0.1f * hw[h] + 1.0f;
        const float o = w * C1c * tanhf(m / C2c);
        const float ii = D1c * tanhf(m / D2c);
        if (h < NHA) {
            if (!ins) { acc[4] += o;  acc[5] += 1.0f; }
            else      { acc[8] += ii; acc[9] += 1.0f; }
        } else {
            if (!ins) { acc[6]  += o;  acc[7]  += 1.0f; }
            else      { acc[10] += ii; acc[11] += 1.0f; }
        }
    }

    __shared__ float red[16][12];
    const int lane = tid & 63;
    const int wave = tid >> 6;
    #pragma unroll
    for (int k = 0; k < 12; ++k) {
        float v = acc[k];
        #pragma unroll
        for (int off = 32; off > 0; off >>= 1)
            v += __shfl_down(v, off);
        acc[k] = v;
    }
    if (lane == 0) {
        #pragma unroll
        for (int k = 0; k < 12; ++k) red[wave][k] = acc[k];
    }
    __syncthreads();
    if (tid == 0) {
        float t[12];
        const int nw = nthr >> 6;
        #pragma unroll
        for (int k = 0; k < 12; ++k) {
            float s = red[0][k];
            for (int w = 1; w < nw; ++w) s += red[w][k];
            t[k] = s;
        }
        const float contactloss = CONTACT_W * (t[0] / fmaxf(t[1], 1.0f));
        const float insideloss  = INSIDE_W  * (t[2] / fmaxf(t[3], 1.0f));
        const float hand_out = t[4] / fmaxf(t[5], 1.0f) + t[6]  / fmaxf(t[7], 1.0f);
        const float hand_in  = t[8] / fmaxf(t[9], 1.0f) + t[10] / fmaxf(t[11], 1.0f);
        out[0] = contactloss + insideloss + HAND_W * (hand_out + hand_in);
    }
}

extern "C" void kernel_launch(void* const* d_in, const int* in_sizes, int n_in,
                              void* d_out, int out_size, void* d_ws, size_t ws_size,
                              hipStream_t stream) {
    const float* vertices = (const float*)d_in[0];  // [1,NV,3]
    const float* geodist  = (const float*)d_in[1];  // [NV,NV]
    const float* hand_w   = (const float*)d_in[2];  // [NHAND]
    const int*   ds       = (const int*)d_in[3];    // [NDS]
    const int*   hand_idx = (const int*)d_in[4];    // [NHAND]
    const int*   cidx     = (const int*)d_in[5];    // [NCONTACT]
    float* out = (float*)d_out;

    // workspace layout (16B-aligned chunks)
    char* p = (char*)d_ws;
    __half2* gxy = (__half2*)p;                 p += ((NV * 4 + 15) & ~15);
    __half* gz = (__half*)p;                    p += ((NV * 2 + 15) & ~15);
    float* hand_min = (float*)p;                p += ((NHAND * 4 + 15) & ~15);
    float* ds_min = (float*)p;                  p += ((NDS * 4 + 15) & ~15);
    float* pgdi = (float*)p;                    p += ((GDI_CHUNKS * NV * 4 + 15) & ~15);
    int* inside = (int*)p;                      p += ((NV * 4 + 15) & ~15);

    dim3 g1(41, 1 + GDI_CHUNKS);
    prep_gdi_kernel<<<g1, 256, 0, stream>>>(vertices, geodist, cidx,
                                            gxy, gz, inside, pgdi);

    scan_kernel<<<SCAN_BLOCKS, SCAN_THREADS, 0, stream>>>(
        geodist, gxy, gz, hand_idx, ds, hand_min, ds_min, inside);

    finalize_kernel<<<1, 1024, 0, stream>>>(ds_min, pgdi, ds, hand_min, hand_w,
                                            hand_idx, inside, out);
}